// Round 8
// baseline (1393.079 us; speedup 1.0000x reference)
//
#include <hip/hip_runtime.h>
#include <math.h>

#define D_MODEL 1024
#define N_HEADS 16
#define D_K 64
#define B_SZ 64
#define S_LEN 2048

// ---------------- kernel 0: qh[b,n] = q[b,:] @ Wq[:,n] + bq[n] ----------------
__global__ __launch_bounds__(256) void k_qh(const float* __restrict__ q,
                                            const float* __restrict__ Wq,
                                            const float* __restrict__ bq,
                                            float* __restrict__ qh) {
    int b = blockIdx.x >> 2;
    int nc = blockIdx.x & 3;
    int t = threadIdx.x;
    __shared__ float ql[D_MODEL];
    ((float4*)ql)[t] = ((const float4*)(q + (size_t)b * D_MODEL))[t];
    __syncthreads();
    int n = nc * 256 + t;
    const float* w = Wq + n;
    float acc = 0.f;
#pragma unroll 8
    for (int d = 0; d < D_MODEL; ++d) acc = fmaf(ql[d], w[(size_t)d * D_MODEL], acc);
    qh[(size_t)b * D_MODEL + n] = acc + bq[n];
}

// ---------------- kernel 1: qt[b,h,d] = (1/8) * sum_j qh[b,h*64+j] * Wk[d, h*64+j] ----------------
__global__ __launch_bounds__(256) void k_qtil(const float* __restrict__ qh,
                                              const float* __restrict__ Wk,
                                              float* __restrict__ qt) {
    int b = blockIdx.x >> 4;
    int h = blockIdx.x & 15;
    int t = threadIdx.x;
    __shared__ float qhl[D_K];
    if (t < 16) ((float4*)qhl)[t] = ((const float4*)(qh + (size_t)b * D_MODEL + h * D_K))[t];
    __syncthreads();
#pragma unroll
    for (int p = 0; p < 4; ++p) {
        int d = p * 256 + t;
        const float* w = Wk + (size_t)d * D_MODEL + h * D_K;
        float acc = 0.f;
#pragma unroll
        for (int j4 = 0; j4 < 16; ++j4) {
            float4 w4 = ((const float4*)w)[j4];
            float4 q4 = ((const float4*)qhl)[j4];
            acc += w4.x * q4.x + w4.y * q4.y + w4.z * q4.z + w4.w * q4.w;
        }
        qt[((size_t)(b * N_HEADS + h)) * D_MODEL + d] = acc * 0.125f;
    }
}

// ---------------- kernel 2: scores + chunk-softmax partials ----------------
// Round-7 lesson: fused A+C at 64 KB LDS pins the WHOLE kernel at 2 blk/CU;
// phases A (wants LDS+pipeline) and C (wants regs+occupancy) fight. Split.
// k_scores: grid 1024 = (64 b x 16 ch), block 512 = 8 waves.
// DCB=32 -> 2x16 KB dbuf -> 4 blk/CU occupancy target -> 64-reg budget,
// pressure ~45: no spill. gload_lds async staging + source-XOR swizzle
// (rule 21: linear LDS dest; swizzle applied identically on src + read).
// Wave w -> head quad (w&3), d-half (w>>2); qt via readfirstlane-uniform
// pointer -> s_load. Chunk-softmax partial P written to GLOBAL sc (8 MB).
#define NCH 16
#define CS 128
#define DCB 32
#define TILE_FB (CS * DCB)  // 4096 floats = 16 KB per buffer
__device__ __forceinline__ void stage_tile(const float* kbase, float* smem, int bufidx,
                                           int dc, int t, int wu) {
#pragma unroll
    for (int p = 0; p < 2; ++p) {
        int idx = t + 512 * p;           // f4 slot index (row*8 + q)
        int row = idx >> 3, q = idx & 7;
        const float* src = kbase + (size_t)row * D_MODEL + dc + 4 * (q ^ (row & 7));
        // dest: wave-uniform base + lane*16; slot = wu*64 + 512p + lane = idx.
        float* dst = smem + bufidx * TILE_FB + (wu * 64 + 512 * p) * 4;
        __builtin_amdgcn_global_load_lds((const __attribute__((address_space(1))) void*)src,
                                         (__attribute__((address_space(3))) void*)dst,
                                         16, 0, 0);
    }
}

__global__ __launch_bounds__(512) void k_scores(const float* __restrict__ k,
                                                const float* __restrict__ qt,
                                                float* __restrict__ sc,
                                                float* __restrict__ ml) {
    __shared__ float smem[2 * TILE_FB];  // 32 KB
    float* red = smem;                   // [4 hq][2 i][4 j][64 lane] scratch after phase A

    int b = blockIdx.x >> 4;
    int ch = blockIdx.x & 15;
    int t = threadIdx.x;
    int w = t >> 6, lane = t & 63;
    int s0 = ch * CS;
    const float* kbase = k + ((size_t)b * S_LEN + s0) * D_MODEL;

    int wu = __builtin_amdgcn_readfirstlane(w);
    int hq = wu & 3, dh = wu >> 2;
    const float* q0 = qt + (size_t)(b * N_HEADS + hq * 4) * D_MODEL + dh * (DCB / 2);

    stage_tile(kbase, smem, 0, 0, t, wu);

    float acc[2][4] = {};
    for (int dcv = 0; dcv < D_MODEL / DCB; ++dcv) {  // 32 tiles
        __syncthreads();  // drains vmcnt -> tile dcv landed; prev-tile reads done
        if (dcv + 1 < D_MODEL / DCB)
            stage_tile(kbase, smem, (dcv + 1) & 1, (dcv + 1) * DCB, t, wu);
        const float* buf = smem + (dcv & 1) * TILE_FB;
        int dc = dcv * DCB;
#pragma unroll
        for (int d4 = 0; d4 < 4; ++d4) {
            float4 qv[4];
#pragma unroll
            for (int j = 0; j < 4; ++j)
                qv[j] = *(const float4*)(q0 + (size_t)j * D_MODEL + dc + 4 * d4);  // s_load
            int cq = dh * 4 + d4;
            int sw = 4 * (cq ^ (lane & 7));  // read-side swizzle (row&7 == lane&7 here)
            float4 kv[2];
#pragma unroll
            for (int i = 0; i < 2; ++i)
                kv[i] = *(const float4*)(buf + (64 * i + lane) * DCB + sw);
#pragma unroll
            for (int i = 0; i < 2; ++i)
#pragma unroll
                for (int j = 0; j < 4; ++j)
                    acc[i][j] = fmaf(kv[i].x, qv[j].x,
                                fmaf(kv[i].y, qv[j].y,
                                fmaf(kv[i].z, qv[j].z,
                                fmaf(kv[i].w, qv[j].w, acc[i][j]))));
        }
    }
    __syncthreads();
    // ---- combine d-halves (waves 4-7 hold upper-d partials) ----
    if (dh == 1) {
#pragma unroll
        for (int i = 0; i < 2; ++i)
#pragma unroll
            for (int j = 0; j < 4; ++j)
                red[((((hq * 2 + i) * 4) + j) << 6) | lane] = acc[i][j];
    }
    __syncthreads();
    // ---- per-head chunk softmax partials (waves 0-3, 4 heads each) ----
    if (dh == 0) {
#pragma unroll
        for (int j = 0; j < 4; ++j) {
            float a0 = acc[0][j] + red[((((hq * 2 + 0) * 4) + j) << 6) | lane];
            float a1 = acc[1][j] + red[((((hq * 2 + 1) * 4) + j) << 6) | lane];
            float m = fmaxf(a0, a1);
#pragma unroll
            for (int o = 32; o; o >>= 1) m = fmaxf(m, __shfl_xor(m, o, 64));
            float p0 = __expf(a0 - m);
            float p1 = __expf(a1 - m);
            float l = p0 + p1;
#pragma unroll
            for (int o = 32; o; o >>= 1) l += __shfl_xor(l, o, 64);
            int h = hq * 4 + j;
            float* scb = sc + (((size_t)(b * NCH + ch)) * N_HEADS + h) * CS;
            scb[lane] = p0;
            scb[64 + lane] = p1;
            if (lane == 0) {
                float* mlp = ml + ((((size_t)ch * B_SZ) + b) * N_HEADS + h) * 2;
                mlp[0] = m;
                mlp[1] = l;
            }
        }
    }
}

// ---------------- kernel 3: partial AV ----------------
// grid 2048 = (64 b x 16 ch x 2 d-halves), block 512 = 8 waves.
// No K-LDS: only the 8 KB P stage -> occupancy target 32 waves/CU ->
// 64-reg budget; oacc[4]=16 regs + v-quad prefetch (~55 total): no spill,
// ~100% occupancy for the big v stream (round-1/4/5 spill lesson respected).
// Thread owns d-float4 (t&127) within its d-half, head-group (t>>7) of 4.
__global__ __launch_bounds__(512) void k_av(const float* __restrict__ v,
                                            const float* __restrict__ sc,
                                            float* __restrict__ part) {
    int b = blockIdx.x >> 5;
    int ch = (blockIdx.x >> 1) & 15;
    int df = blockIdx.x & 1;
    int t = threadIdx.x;
    __shared__ float al[N_HEADS * CS];  // 8 KB
    {
        int h = t >> 5, s4 = t & 31;
        *(float4*)(al + h * CS + 4 * s4) =
            *(const float4*)(sc + (((size_t)(b * NCH + ch)) * N_HEADS + h) * CS + 4 * s4);
    }
    __syncthreads();
    int d4i = t & 127;
    int hg = t >> 7;  // 0..3 -> heads hg*4 .. hg*4+3
    float4 oacc[4];
#pragma unroll
    for (int hh = 0; hh < 4; ++hh) oacc[hh] = make_float4(0.f, 0.f, 0.f, 0.f);
    const float* vbase = v + ((size_t)b * S_LEN + ch * CS) * D_MODEL + df * 512 + 4 * d4i;
    const float* plb = al + (hg * 4) * CS;
    float4 vr0 = *(const float4*)(vbase + (size_t)0 * D_MODEL);
    float4 vr1 = *(const float4*)(vbase + (size_t)1 * D_MODEL);
    float4 vr2 = *(const float4*)(vbase + (size_t)2 * D_MODEL);
    float4 vr3 = *(const float4*)(vbase + (size_t)3 * D_MODEL);
    for (int sg = 0; sg < CS / 4; ++sg) {
        float4 v0 = vr0, v1 = vr1, v2 = vr2, v3 = vr3;
        if (sg + 1 < CS / 4) {
            vr0 = *(const float4*)(vbase + (size_t)(4 * sg + 4) * D_MODEL);
            vr1 = *(const float4*)(vbase + (size_t)(4 * sg + 5) * D_MODEL);
            vr2 = *(const float4*)(vbase + (size_t)(4 * sg + 6) * D_MODEL);
            vr3 = *(const float4*)(vbase + (size_t)(4 * sg + 7) * D_MODEL);
        }
#pragma unroll
        for (int hh = 0; hh < 4; ++hh) {
            float4 a4 = *(const float4*)(plb + hh * CS + 4 * sg);  // wave-uniform broadcast
            oacc[hh].x = fmaf(a4.x, v0.x, fmaf(a4.y, v1.x, fmaf(a4.z, v2.x, fmaf(a4.w, v3.x, oacc[hh].x))));
            oacc[hh].y = fmaf(a4.x, v0.y, fmaf(a4.y, v1.y, fmaf(a4.z, v2.y, fmaf(a4.w, v3.y, oacc[hh].y))));
            oacc[hh].z = fmaf(a4.x, v0.z, fmaf(a4.y, v1.z, fmaf(a4.z, v2.z, fmaf(a4.w, v3.z, oacc[hh].z))));
            oacc[hh].w = fmaf(a4.x, v0.w, fmaf(a4.y, v1.w, fmaf(a4.z, v2.w, fmaf(a4.w, v3.w, oacc[hh].w))));
        }
    }
#pragma unroll
    for (int hh = 0; hh < 4; ++hh)
        *(float4*)(part + ((((size_t)ch * B_SZ) + b) * N_HEADS + hg * 4 + hh) * D_MODEL
                   + df * 512 + 4 * d4i) = oacc[hh];
}

// ---------------- kernel 4: cross-chunk combine + Wv projection ----------------
__global__ __launch_bounds__(64) void k_cc(const float* __restrict__ part,
                                           const float* __restrict__ ml,
                                           const float* __restrict__ Wv,
                                           const float* __restrict__ bv,
                                           float* __restrict__ cc) {
    int b = blockIdx.x >> 4, h = blockIdx.x & 15;
    int lane = threadIdx.x;
    __shared__ float vt[D_MODEL];
    float m[NCH], lw[NCH];
    float M = -3.4e38f;
#pragma unroll
    for (int ch = 0; ch < NCH; ++ch) {
        const float* mlp = ml + ((((size_t)ch * B_SZ) + b) * N_HEADS + h) * 2;
        m[ch] = mlp[0];
        lw[ch] = mlp[1];
        M = fmaxf(M, m[ch]);
    }
    float L = 0.f;
#pragma unroll
    for (int ch = 0; ch < NCH; ++ch) {
        m[ch] = __expf(m[ch] - M);
        L += lw[ch] * m[ch];
    }
    float inv = 1.0f / L;
#pragma unroll
    for (int p = 0; p < 4; ++p) {
        int i4 = lane + 64 * p;
        float4 s = make_float4(0.f, 0.f, 0.f, 0.f);
#pragma unroll
        for (int ch = 0; ch < NCH; ++ch) {
            float4 x = *(const float4*)(part + ((((size_t)ch * B_SZ) + b) * N_HEADS + h) * D_MODEL + 4 * i4);
            s.x = fmaf(m[ch], x.x, s.x);
            s.y = fmaf(m[ch], x.y, s.y);
            s.z = fmaf(m[ch], x.z, s.z);
            s.w = fmaf(m[ch], x.w, s.w);
        }
        s.x *= inv; s.y *= inv; s.z *= inv; s.w *= inv;
        *(float4*)(vt + 4 * i4) = s;
    }
    __syncthreads();
    const float* wv = Wv + h * D_K + lane;
    float acc = 0.f;
#pragma unroll 8
    for (int d = 0; d < D_MODEL; ++d) acc = fmaf(vt[d], wv[(size_t)d * D_MODEL], acc);
    cc[(size_t)b * D_MODEL + h * D_K + lane] = acc + bv[h * D_K + lane];
}

// ---------------- kernel 5: out[b,n] = relu(cc[b,:] @ Wo[:,n] + bo[n]) ----------------
__global__ __launch_bounds__(256) void k_out(const float* __restrict__ cc,
                                             const float* __restrict__ Wo,
                                             const float* __restrict__ bo,
                                             float* __restrict__ out) {
    int b = blockIdx.x >> 2, nc = blockIdx.x & 3;
    int t = threadIdx.x;
    __shared__ float cl[D_MODEL];
    ((float4*)cl)[t] = ((const float4*)(cc + (size_t)b * D_MODEL))[t];
    __syncthreads();
    int n = nc * 256 + t;
    const float* w = Wo + n;
    float acc = 0.f;
#pragma unroll 8
    for (int m = 0; m < D_MODEL; ++m) acc = fmaf(cl[m], w[(size_t)m * D_MODEL], acc);
    float r = acc + bo[n];
    out[(size_t)b * D_MODEL + n] = r > 0.f ? r : 0.f;
}

extern "C" void kernel_launch(void* const* d_in, const int* in_sizes, int n_in,
                              void* d_out, int out_size, void* d_ws, size_t ws_size,
                              hipStream_t stream) {
    const float* q  = (const float*)d_in[0];
    const float* k  = (const float*)d_in[1];
    const float* v  = (const float*)d_in[2];
    const float* Wq = (const float*)d_in[3];
    const float* bq = (const float*)d_in[4];
    const float* Wk = (const float*)d_in[5];
    // d_in[6] = bk: unused — softmax is shift-invariant, qh.bk is constant per (b,h) row
    const float* Wv = (const float*)d_in[7];
    const float* bv = (const float*)d_in[8];
    const float* Wo = (const float*)d_in[9];
    const float* bo = (const float*)d_in[10];
    float* out = (float*)d_out;

    float* ws = (float*)d_ws;
    float* qh   = ws;                       // 65,536 f
    float* qt   = qh + 65536;               // 1,048,576 f
    float* part = qt + 1048576;             // 16,777,216 f  (NCH*B*H*D_MODEL)
    float* ml   = part + 16777216;          // 32,768 f      (NCH*B*H*2)
    float* sc   = ml + 32768;               // 2,097,152 f   (B*NCH*H*CS)
    float* cc   = sc + 2097152;             // 65,536 f      (total ~80 MB)

    k_qh<<<256, 256, 0, stream>>>(q, Wq, bq, qh);
    k_qtil<<<1024, 256, 0, stream>>>(qh, Wk, qt);
    k_scores<<<1024, 512, 0, stream>>>(k, qt, sc, ml);
    k_av<<<2048, 512, 0, stream>>>(v, sc, part);
    k_cc<<<1024, 64, 0, stream>>>(part, ml, Wv, bv, cc);
    k_out<<<256, 256, 0, stream>>>(cc, Wo, bo, out);
}

// Round 12
// 1325.033 us; speedup vs baseline: 1.0514x; 1.0514x over previous
//
#include <hip/hip_runtime.h>
#include <math.h>

#define D_MODEL 1024
#define N_HEADS 16
#define D_K 64
#define B_SZ 64
#define S_LEN 2048

// ---------------- kernel 0: qh[b,n] = q[b,:] @ Wq[:,n] + bq[n] ----------------
__global__ __launch_bounds__(256) void k_qh(const float* __restrict__ q,
                                            const float* __restrict__ Wq,
                                            const float* __restrict__ bq,
                                            float* __restrict__ qh) {
    int b = blockIdx.x >> 2;
    int nc = blockIdx.x & 3;
    int t = threadIdx.x;
    __shared__ float ql[D_MODEL];
    ((float4*)ql)[t] = ((const float4*)(q + (size_t)b * D_MODEL))[t];
    __syncthreads();
    int n = nc * 256 + t;
    const float* w = Wq + n;
    float acc = 0.f;
#pragma unroll 8
    for (int d = 0; d < D_MODEL; ++d) acc = fmaf(ql[d], w[(size_t)d * D_MODEL], acc);
    qh[(size_t)b * D_MODEL + n] = acc + bq[n];
}

// ---------------- kernel 1: qt[b,h,d] = (1/8) * sum_j qh[b,h*64+j] * Wk[d, h*64+j] ----------------
__global__ __launch_bounds__(256) void k_qtil(const float* __restrict__ qh,
                                              const float* __restrict__ Wk,
                                              float* __restrict__ qt) {
    int b = blockIdx.x >> 4;
    int h = blockIdx.x & 15;
    int t = threadIdx.x;
    __shared__ float qhl[D_K];
    if (t < 16) ((float4*)qhl)[t] = ((const float4*)(qh + (size_t)b * D_MODEL + h * D_K))[t];
    __syncthreads();
#pragma unroll
    for (int p = 0; p < 4; ++p) {
        int d = p * 256 + t;
        const float* w = Wk + (size_t)d * D_MODEL + h * D_K;
        float acc = 0.f;
#pragma unroll
        for (int j4 = 0; j4 < 16; ++j4) {
            float4 w4 = ((const float4*)w)[j4];
            float4 q4 = ((const float4*)qhl)[j4];
            acc += w4.x * q4.x + w4.y * q4.y + w4.z * q4.z + w4.w * q4.w;
        }
        qt[((size_t)(b * N_HEADS + h)) * D_MODEL + d] = acc * 0.125f;
    }
}

// ---------------- kernel 2: fused flash-decode chunk ----------------
// ROUND-7 VERBATIM (verified passing, 1325.7 us total). Rounds 8-11 tried a
// 1024-thread re-parameterization for full occupancy; 3 consecutive
// correctness failures (round-9 qt offset bug fixed, round-10 gload_lds
// wave-uniform-dest bug fixed, a third defect never localized). Reverting
// per the pre-committed fallback: this structure is the session's floor.
// grid 1024 = (64 b x 16 s-chunks of 128), block 512 = 8 waves.
// Async staging via __builtin_amdgcn_global_load_lds (width 16) +
// double-buffered 64 KB LDS; source-side XOR swizzle (linear LDS dest,
// rule 21), read-side same involution. 2-phase {barrier; stage next;
// compute cur} pipeline. Phase A: wave w -> head quad (w&3), d-half (w>>2);
// qt via readfirstlane-uniform pointer -> s_load. Phase A': cross-wave
// d-half reduction. Phase B: waves 0-3 per-head chunk max/sum -> pl.
// Phase C: thread (t&255) owns d-float4, (t>>8) picks head-group of 8;
// oacc[8] + v-quad prefetch (T14).
#define NCH 16
#define CS 128
#define DCA 64
#define TILE_F (CS * DCA)  // 8192 floats = 32 KB per buffer
__device__ __forceinline__ void stage_tile(const float* kbase, float* smem, int bufidx,
                                           int dc, int t, int wu) {
#pragma unroll
    for (int p = 0; p < 4; ++p) {
        int idx = t + 512 * p;           // lds quad index (row*16 + q)
        int row = idx >> 4, q = idx & 15;
        const float* src = kbase + (size_t)row * D_MODEL + dc + 4 * (q ^ (row & 7));
        // dest: wave-uniform base + lane*16 (hardware semantics); lane's slot
        // matches idx since idx = wu*64 + 512p + lane.
        float* dst = smem + bufidx * TILE_F + (wu * 64 + 512 * p) * 4;
        __builtin_amdgcn_global_load_lds((const __attribute__((address_space(1))) void*)src,
                                         (__attribute__((address_space(3))) void*)dst,
                                         16, 0, 0);
    }
}

__global__ __launch_bounds__(512) void k_attn(const float* __restrict__ k,
                                              const float* __restrict__ v,
                                              const float* __restrict__ qt,
                                              float* __restrict__ part,
                                              float* __restrict__ ml) {
    __shared__ float smem[2 * TILE_F];  // 64 KB double buffer
    float* pl = smem;                   // [16 h][128 s] after phase A (8 KB, in buf0)
    float* red = smem + 4096;           // [4 hq][2 i][4 j][64 lane] scratch (in buf0)

    int b = blockIdx.x >> 4;
    int ch = blockIdx.x & 15;
    int t = threadIdx.x;
    int w = t >> 6, lane = t & 63;
    int s0 = ch * CS;
    const float* kbase = k + ((size_t)b * S_LEN + s0) * D_MODEL;

    // wave-uniform head-quad / d-half (SGPR-hoisted so qt loads scalarize)
    int wu = __builtin_amdgcn_readfirstlane(w);
    int hq = wu & 3, dh = wu >> 2;
    const float* q0 = qt + (size_t)(b * N_HEADS + hq * 4) * D_MODEL + dh * (DCA / 2);

    // prologue: stage tile 0
    stage_tile(kbase, smem, 0, 0, t, wu);

    float acc[2][4] = {};
    for (int dcv = 0; dcv < D_MODEL / DCA; ++dcv) {
        __syncthreads();  // drains vmcnt -> tile dcv landed; prev-tile reads done
        if (dcv + 1 < D_MODEL / DCA)
            stage_tile(kbase, smem, (dcv + 1) & 1, (dcv + 1) * DCA, t, wu);
        const float* buf = smem + (dcv & 1) * TILE_F;
        int dc = dcv * DCA;
#pragma unroll
        for (int d4 = 0; d4 < 8; ++d4) {
            float4 qv[4];
#pragma unroll
            for (int j = 0; j < 4; ++j)
                qv[j] = *(const float4*)(q0 + (size_t)j * D_MODEL + dc + 4 * d4);  // s_load
            int sw = 4 * ((dh * 8 + d4) ^ (lane & 7));  // read-side swizzle (involution)
            float4 kv[2];
#pragma unroll
            for (int i = 0; i < 2; ++i)
                kv[i] = *(const float4*)(buf + (64 * i + lane) * DCA + sw);
#pragma unroll
            for (int i = 0; i < 2; ++i)
#pragma unroll
                for (int j = 0; j < 4; ++j)
                    acc[i][j] = fmaf(kv[i].x, qv[j].x,
                                fmaf(kv[i].y, qv[j].y,
                                fmaf(kv[i].z, qv[j].z,
                                fmaf(kv[i].w, qv[j].w, acc[i][j]))));
        }
    }
    __syncthreads();
    // ---- phase A': combine d-halves (waves 4-7 hold the upper-d partials) ----
    if (dh == 1) {
#pragma unroll
        for (int i = 0; i < 2; ++i)
#pragma unroll
            for (int j = 0; j < 4; ++j)
                red[((((hq * 2 + i) * 4) + j) << 6) | lane] = acc[i][j];
    }
    __syncthreads();
    // ---- phase B: per-head chunk softmax partials (waves 0-3, 4 heads each) ----
    if (dh == 0) {
#pragma unroll
        for (int j = 0; j < 4; ++j) {
            float a0 = acc[0][j] + red[((((hq * 2 + 0) * 4) + j) << 6) | lane];
            float a1 = acc[1][j] + red[((((hq * 2 + 1) * 4) + j) << 6) | lane];
            float m = fmaxf(a0, a1);
#pragma unroll
            for (int o = 32; o; o >>= 1) m = fmaxf(m, __shfl_xor(m, o, 64));
            float p0 = __expf(a0 - m);
            float p1 = __expf(a1 - m);
            float l = p0 + p1;
#pragma unroll
            for (int o = 32; o; o >>= 1) l += __shfl_xor(l, o, 64);
            int h = hq * 4 + j;
            pl[h * CS + lane] = p0;
            pl[h * CS + 64 + lane] = p1;
            if (lane == 0) {
                float* mlp = ml + ((((size_t)ch * B_SZ) + b) * N_HEADS + h) * 2;
                mlp[0] = m;
                mlp[1] = l;
            }
        }
    }
    __syncthreads();
    // ---- phase C: partial AV with v-quad prefetch (T14) ----
    int d4i = t & 255;
    int hg = t >> 8;  // 0 or 1 -> heads hg*8 .. hg*8+7
    float4 oacc[8];
#pragma unroll
    for (int hh = 0; hh < 8; ++hh) oacc[hh] = make_float4(0.f, 0.f, 0.f, 0.f);
    const float* vbase = v + ((size_t)b * S_LEN + s0) * D_MODEL + 4 * d4i;
    const float* plb = pl + (hg * 8) * CS;
    float4 vr0 = *(const float4*)(vbase + (size_t)0 * D_MODEL);
    float4 vr1 = *(const float4*)(vbase + (size_t)1 * D_MODEL);
    float4 vr2 = *(const float4*)(vbase + (size_t)2 * D_MODEL);
    float4 vr3 = *(const float4*)(vbase + (size_t)3 * D_MODEL);
    for (int sg = 0; sg < CS / 4; ++sg) {
        float4 v0 = vr0, v1 = vr1, v2 = vr2, v3 = vr3;
        if (sg + 1 < CS / 4) {
            vr0 = *(const float4*)(vbase + (size_t)(4 * sg + 4) * D_MODEL);
            vr1 = *(const float4*)(vbase + (size_t)(4 * sg + 5) * D_MODEL);
            vr2 = *(const float4*)(vbase + (size_t)(4 * sg + 6) * D_MODEL);
            vr3 = *(const float4*)(vbase + (size_t)(4 * sg + 7) * D_MODEL);
        }
#pragma unroll
        for (int hh = 0; hh < 8; ++hh) {
            float4 a4 = *(const float4*)(plb + hh * CS + 4 * sg);  // wave-uniform broadcast
            oacc[hh].x = fmaf(a4.x, v0.x, fmaf(a4.y, v1.x, fmaf(a4.z, v2.x, fmaf(a4.w, v3.x, oacc[hh].x))));
            oacc[hh].y = fmaf(a4.x, v0.y, fmaf(a4.y, v1.y, fmaf(a4.z, v2.y, fmaf(a4.w, v3.y, oacc[hh].y))));
            oacc[hh].z = fmaf(a4.x, v0.z, fmaf(a4.y, v1.z, fmaf(a4.z, v2.z, fmaf(a4.w, v3.z, oacc[hh].z))));
            oacc[hh].w = fmaf(a4.x, v0.w, fmaf(a4.y, v1.w, fmaf(a4.z, v2.w, fmaf(a4.w, v3.w, oacc[hh].w))));
        }
    }
#pragma unroll
    for (int hh = 0; hh < 8; ++hh)
        *(float4*)(part + ((((size_t)ch * B_SZ) + b) * N_HEADS + hg * 8 + hh) * D_MODEL + 4 * d4i) = oacc[hh];
}

// ---------------- kernel 3: cross-chunk combine + Wv projection ----------------
__global__ __launch_bounds__(64) void k_cc(const float* __restrict__ part,
                                           const float* __restrict__ ml,
                                           const float* __restrict__ Wv,
                                           const float* __restrict__ bv,
                                           float* __restrict__ cc) {
    int b = blockIdx.x >> 4, h = blockIdx.x & 15;
    int lane = threadIdx.x;
    __shared__ float vt[D_MODEL];
    float m[NCH], lw[NCH];
    float M = -3.4e38f;
#pragma unroll
    for (int ch = 0; ch < NCH; ++ch) {
        const float* mlp = ml + ((((size_t)ch * B_SZ) + b) * N_HEADS + h) * 2;
        m[ch] = mlp[0];
        lw[ch] = mlp[1];
        M = fmaxf(M, m[ch]);
    }
    float L = 0.f;
#pragma unroll
    for (int ch = 0; ch < NCH; ++ch) {
        m[ch] = __expf(m[ch] - M);
        L += lw[ch] * m[ch];
    }
    float inv = 1.0f / L;
#pragma unroll
    for (int p = 0; p < 4; ++p) {
        int i4 = lane + 64 * p;
        float4 s = make_float4(0.f, 0.f, 0.f, 0.f);
#pragma unroll
        for (int ch = 0; ch < NCH; ++ch) {
            float4 x = *(const float4*)(part + ((((size_t)ch * B_SZ) + b) * N_HEADS + h) * D_MODEL + 4 * i4);
            s.x = fmaf(m[ch], x.x, s.x);
            s.y = fmaf(m[ch], x.y, s.y);
            s.z = fmaf(m[ch], x.z, s.z);
            s.w = fmaf(m[ch], x.w, s.w);
        }
        s.x *= inv; s.y *= inv; s.z *= inv; s.w *= inv;
        *(float4*)(vt + 4 * i4) = s;
    }
    __syncthreads();
    const float* wv = Wv + h * D_K + lane;
    float acc = 0.f;
#pragma unroll 8
    for (int d = 0; d < D_MODEL; ++d) acc = fmaf(vt[d], wv[(size_t)d * D_MODEL], acc);
    cc[(size_t)b * D_MODEL + h * D_K + lane] = acc + bv[h * D_K + lane];
}

// ---------------- kernel 4: out[b,n] = relu(cc[b,:] @ Wo[:,n] + bo[n]) ----------------
__global__ __launch_bounds__(256) void k_out(const float* __restrict__ cc,
                                             const float* __restrict__ Wo,
                                             const float* __restrict__ bo,
                                             float* __restrict__ out) {
    int b = blockIdx.x >> 2, nc = blockIdx.x & 3;
    int t = threadIdx.x;
    __shared__ float cl[D_MODEL];
    ((float4*)cl)[t] = ((const float4*)(cc + (size_t)b * D_MODEL))[t];
    __syncthreads();
    int n = nc * 256 + t;
    const float* w = Wo + n;
    float acc = 0.f;
#pragma unroll 8
    for (int m = 0; m < D_MODEL; ++m) acc = fmaf(cl[m], w[(size_t)m * D_MODEL], acc);
    float r = acc + bo[n];
    out[(size_t)b * D_MODEL + n] = r > 0.f ? r : 0.f;
}

extern "C" void kernel_launch(void* const* d_in, const int* in_sizes, int n_in,
                              void* d_out, int out_size, void* d_ws, size_t ws_size,
                              hipStream_t stream) {
    const float* q  = (const float*)d_in[0];
    const float* k  = (const float*)d_in[1];
    const float* v  = (const float*)d_in[2];
    const float* Wq = (const float*)d_in[3];
    const float* bq = (const float*)d_in[4];
    const float* Wk = (const float*)d_in[5];
    // d_in[6] = bk: unused — softmax is shift-invariant, qh.bk is constant per (b,h) row
    const float* Wv = (const float*)d_in[7];
    const float* bv = (const float*)d_in[8];
    const float* Wo = (const float*)d_in[9];
    const float* bo = (const float*)d_in[10];
    float* out = (float*)d_out;

    float* ws = (float*)d_ws;
    float* qh   = ws;                       // 65,536 f
    float* qt   = qh + 65536;               // 1,048,576 f
    float* part = qt + 1048576;             // 16,777,216 f  (NCH*B*H*D_MODEL)
    float* ml   = part + 16777216;          // 32,768 f      (NCH*B*H*2)
    float* cc   = ml + 32768;               // 65,536 f      (total ~72 MB)

    k_qh<<<256, 256, 0, stream>>>(q, Wq, bq, qh);
    k_qtil<<<1024, 256, 0, stream>>>(qh, Wk, qt);
    k_attn<<<1024, 512, 0, stream>>>(k, v, qt, part, ml);
    k_cc<<<1024, 64, 0, stream>>>(part, ml, Wv, bv, cc);
    k_out<<<256, 256, 0, stream>>>(cc, Wo, bo, out);
}